// Round 9
// baseline (46.019 us; speedup 1.0000x reference)
//
#include <hip/hip_runtime.h>

// L=32768, N=32, E=H=1, BS=256 -> 4096 rank-1 softmax problems:
//   s_ij = a_i*k_j (scale=1), out_i = sum_j 2^(a'_i k_j) v_j / sum_j 2^(a'_i k_j),
//   a' = a*log2e. No max-subtraction: |arg| <= ~39 log2 units, f32-safe,
//   softmax scale-invariant (validated R5-R8).
//
// R9: R8 was issue-bound at 64% efficiency; idle = scattered prologue gathers
// at 4.6 waves/SIMD residency. This version: 2048 WGs x 256 thr (8 WG/CU =
// 100% occupancy), ALL global I/O coalesced, k/v tiled through LDS [32j][32n]
// (conflict-free: 32 banks + 2-way broadcast), one-tile-ahead reg prefetch.
// Each thread owns 2 rows x 1 batch: per j = 6 VALU + 2 exp.

#define LL    32768
#define NN    32
#define BSZ   256
#define NBLK  (LL / BSZ)        // 128
#define RG    16                // rows per workgroup
#define NRG   (BSZ / RG)        // 16 row-groups per block
#define TJ    32                // j-tile size
#define NT    (BSZ / TJ)        // 8 tiles... (256/32 = 8)  [loop count below]
#define LOG2E 1.4426950408889634f

__global__ __launch_bounds__(256) void BlockCrossAttn_kernel(
    const float* __restrict__ q_in, const float* __restrict__ k_in,
    const float* __restrict__ v_in,
    const float* __restrict__ ipw,  const float* __restrict__ ipb,
    const float* __restrict__ opw,  const float* __restrict__ opb,
    float* __restrict__ out)
{
    const int id  = blockIdx.x;
    const int blk = id & (NBLK - 1);   // consecutive ids -> consecutive blk:
    const int rg  = id >> 7;           // all row-groups of a blk on XCD blk%8
    const int t   = threadIdx.x;
    const int n   = t & 31;
    const int rp  = t >> 5;            // 0..7 -> rows rg*RG + rp*2 + {0,1}

    const float wq = ipw[0], wk = ipw[1], wv = ipw[2];
    const float bq = ipb[0], bk = ipb[1], bv = ipb[2];

    __shared__ alignas(16) float sk[TJ * NN];   // [j][n]
    __shared__ alignas(16) float sv[TJ * NN];
    __shared__ alignas(16) float sa[RG * NN];   // [row][n]

    const int slab = blk * BSZ * NN;            // flat base of this block's rows

    // ---- stage q (rows rg*RG .. +16) : coalesced, half the threads ----
    if (t < (RG * NN) / 4) {
        const float4 q4 = *reinterpret_cast<const float4*>(q_in + slab + rg * RG * NN + t * 4);
        float4 a4;
        a4.x = fmaf(q4.x, wq, bq) * LOG2E;
        a4.y = fmaf(q4.y, wq, bq) * LOG2E;
        a4.z = fmaf(q4.z, wq, bq) * LOG2E;
        a4.w = fmaf(q4.w, wq, bq) * LOG2E;
        *reinterpret_cast<float4*>(sa + t * 4) = a4;
    }

    // ---- stage tile 0 of k/v : coalesced, 1 float4 per thread per array ----
    {
        const float4 k4 = *reinterpret_cast<const float4*>(k_in + slab + t * 4);
        const float4 v4 = *reinterpret_cast<const float4*>(v_in + slab + t * 4);
        float4 kp, vp;
        kp.x = fmaf(k4.x, wk, bk); kp.y = fmaf(k4.y, wk, bk);
        kp.z = fmaf(k4.z, wk, bk); kp.w = fmaf(k4.w, wk, bk);
        vp.x = fmaf(v4.x, wv, bv); vp.y = fmaf(v4.y, wv, bv);
        vp.z = fmaf(v4.z, wv, bv); vp.w = fmaf(v4.w, wv, bv);
        *reinterpret_cast<float4*>(sk + t * 4) = kp;
        *reinterpret_cast<float4*>(sv + t * 4) = vp;
    }
    __syncthreads();

    const float a0 = sa[(rp * 2 + 0) * NN + n];
    const float a1 = sa[(rp * 2 + 1) * NN + n];

    float den0 = 0.f, den1 = 0.f, num0 = 0.f, num1 = 0.f;

    #pragma unroll 1
    for (int tt = 0; tt < BSZ / TJ; ++tt) {
        // prefetch next tile into regs (VMEM issued here, waited at write)
        float4 kn, vn;
        const bool more = (tt + 1) < (BSZ / TJ);
        if (more) {
            kn = *reinterpret_cast<const float4*>(k_in + slab + (tt + 1) * TJ * NN + t * 4);
            vn = *reinterpret_cast<const float4*>(v_in + slab + (tt + 1) * TJ * NN + t * 4);
        }

        // compute current tile: lanes read 32 distinct banks (+2-way bcast)
        #pragma unroll
        for (int j = 0; j < TJ; ++j) {
            const float kj = sk[j * NN + n];
            const float vj = sv[j * NN + n];
            const float p0 = __builtin_amdgcn_exp2f(a0 * kj);
            const float p1 = __builtin_amdgcn_exp2f(a1 * kj);
            den0 += p0; den1 += p1;
            num0 = fmaf(p0, vj, num0);
            num1 = fmaf(p1, vj, num1);
        }
        __syncthreads();
        if (more) {
            float4 kp, vp;
            kp.x = fmaf(kn.x, wk, bk); kp.y = fmaf(kn.y, wk, bk);
            kp.z = fmaf(kn.z, wk, bk); kp.w = fmaf(kn.w, wk, bk);
            vp.x = fmaf(vn.x, wv, bv); vp.y = fmaf(vn.y, wv, bv);
            vp.z = fmaf(vn.z, wv, bv); vp.w = fmaf(vn.w, wv, bv);
            *reinterpret_cast<float4*>(sk + t * 4) = kp;
            *reinterpret_cast<float4*>(sv + t * 4) = vp;
            __syncthreads();
        }
    }

    const float wo = opw[0], bo = opb[0];
    const int r0 = blk * BSZ + rg * RG + rp * 2;
    out[(size_t)(r0 + 0) * NN + n] = fmaf(num0 / den0, wo, bo);
    out[(size_t)(r0 + 1) * NN + n] = fmaf(num1 / den1, wo, bo);
}

extern "C" void kernel_launch(void* const* d_in, const int* in_sizes, int n_in,
                              void* d_out, int out_size, void* d_ws, size_t ws_size,
                              hipStream_t stream) {
    const float* q   = (const float*)d_in[0];
    const float* k   = (const float*)d_in[1];
    const float* v   = (const float*)d_in[2];
    const float* ipw = (const float*)d_in[3];
    const float* ipb = (const float*)d_in[4];
    const float* opw = (const float*)d_in[5];
    const float* opb = (const float*)d_in[6];
    float* out = (float*)d_out;

    dim3 grid(NBLK * NRG);   // 2048 WGs: rowgroup-major (blk = id & 127)
    dim3 block(256);
    BlockCrossAttn_kernel<<<grid, block, 0, stream>>>(q, k, v, ipw, ipb, opw, opb, out);
}

// Round 10
// 41.769 us; speedup vs baseline: 1.1018x; 1.1018x over previous
//
#include <hip/hip_runtime.h>

// L=32768, N=32, E=H=1, BS=256 -> 4096 rank-1 softmax problems:
//   s_ij = a_i*k_j (scale=1), out_i = sum_j 2^(a'_i k_j) v_j / sum_j 2^(a'_i k_j),
//   a' = a*log2e. No max-subtraction: |arg| <= ~39 log2 units, f32-safe,
//   softmax scale-invariant (validated R5-R9).
//
// R10 = R8 (best, 41.8us) + two levers:
//  (a) 2 problems per WG (p0=g, p1=g+2048; same n): all 6 scattered gathers
//      issue up front, P1's latency hides under P0's ~5.5k-cy inner loop.
//  (b) inner loop in v2f vector IR -> v_pk_{mul,add,fma}_f32 if the backend
//      packs (R6 proved scalarization is cost-neutral, so downside is zero).
// Model: busy/SIMD = 16w x 256j x (3cy pkVALU + 10.3cy exp) ~ 57k cy; R8
// wall was 105k with 38k idle from exposed prologue gathers.

#define LL    32768
#define NN    32
#define BSZ   256
#define NBLK  (LL / BSZ)
#define LOG2E 1.4426950408889634f

typedef float v2f __attribute__((ext_vector_type(2)));

__global__ __launch_bounds__(256) void BlockCrossAttn_kernel(
    const float* __restrict__ q_in, const float* __restrict__ k_in,
    const float* __restrict__ v_in,
    const float* __restrict__ ipw,  const float* __restrict__ ipb,
    const float* __restrict__ opw,  const float* __restrict__ opb,
    float* __restrict__ out)
{
    const int g   = blockIdx.x;        // 0..2047
    const int n   = g & 31;            // batch (same for both problems)
    const int blk0 = g >> 5;           // row-blocks 0..63
    const int blk1 = blk0 + 64;        // row-blocks 64..127
    const int tid = threadIdx.x;

    const float wq = ipw[0], wk = ipw[1], wv = ipw[2];
    const float bq = ipb[0], bk = ipb[1], bv = ipb[2];
    const float wo = opw[0], bo = opb[0];

    __shared__ alignas(16) float sk[BSZ];
    __shared__ alignas(16) float sv[BSZ];

    const int gidx0 = (blk0 * BSZ + tid) * NN + n;
    const int gidx1 = (blk1 * BSZ + tid) * NN + n;

    // Issue ALL gathers up front; per-use vmcnt waits let P1 loads stay in
    // flight across P0's entire inner loop.
    const float q0 = q_in[gidx0];
    const float k0 = k_in[gidx0];
    const float v0 = v_in[gidx0];
    const float q1 = q_in[gidx1];
    const float k1 = k_in[gidx1];
    const float v1 = v_in[gidx1];

    // ---------------- problem 0 ----------------
    {
        const float a = fmaf(q0, wq, bq) * LOG2E;
        sk[tid] = fmaf(k0, wk, bk);
        sv[tid] = fmaf(v0, wv, bv);
        __syncthreads();

        const v2f a2 = {a, a};
        v2f den01 = {0.f, 0.f}, den23 = {0.f, 0.f};
        v2f num01 = {0.f, 0.f}, num23 = {0.f, 0.f};
        const float4* __restrict__ k4p = (const float4*)sk;
        const float4* __restrict__ v4p = (const float4*)sv;

        #pragma unroll 4
        for (int t = 0; t < BSZ / 4; ++t) {
            const float4 k4 = k4p[t];   // uniform ds_read_b128 (broadcast)
            const float4 v4 = v4p[t];
            const v2f argA = a2 * (v2f){k4.x, k4.y};
            const v2f argB = a2 * (v2f){k4.z, k4.w};
            v2f pA, pB;
            pA.x = __builtin_amdgcn_exp2f(argA.x);
            pA.y = __builtin_amdgcn_exp2f(argA.y);
            pB.x = __builtin_amdgcn_exp2f(argB.x);
            pB.y = __builtin_amdgcn_exp2f(argB.y);
            den01 += pA; den23 += pB;
            num01 = __builtin_elementwise_fma(pA, (v2f){v4.x, v4.y}, num01);
            num23 = __builtin_elementwise_fma(pB, (v2f){v4.z, v4.w}, num23);
        }

        const float den = (den01.x + den01.y) + (den23.x + den23.y);
        const float num = (num01.x + num01.y) + (num23.x + num23.y);
        out[gidx0] = fmaf(num / den, wo, bo);
    }

    // ---------------- problem 1 ----------------
    __syncthreads();   // everyone done reading P0's sk/sv
    {
        const float a = fmaf(q1, wq, bq) * LOG2E;
        sk[tid] = fmaf(k1, wk, bk);
        sv[tid] = fmaf(v1, wv, bv);
        __syncthreads();

        const v2f a2 = {a, a};
        v2f den01 = {0.f, 0.f}, den23 = {0.f, 0.f};
        v2f num01 = {0.f, 0.f}, num23 = {0.f, 0.f};
        const float4* __restrict__ k4p = (const float4*)sk;
        const float4* __restrict__ v4p = (const float4*)sv;

        #pragma unroll 4
        for (int t = 0; t < BSZ / 4; ++t) {
            const float4 k4 = k4p[t];
            const float4 v4 = v4p[t];
            const v2f argA = a2 * (v2f){k4.x, k4.y};
            const v2f argB = a2 * (v2f){k4.z, k4.w};
            v2f pA, pB;
            pA.x = __builtin_amdgcn_exp2f(argA.x);
            pA.y = __builtin_amdgcn_exp2f(argA.y);
            pB.x = __builtin_amdgcn_exp2f(argB.x);
            pB.y = __builtin_amdgcn_exp2f(argB.y);
            den01 += pA; den23 += pB;
            num01 = __builtin_elementwise_fma(pA, (v2f){v4.x, v4.y}, num01);
            num23 = __builtin_elementwise_fma(pB, (v2f){v4.z, v4.w}, num23);
        }

        const float den = (den01.x + den01.y) + (den23.x + den23.y);
        const float num = (num01.x + num01.y) + (num23.x + num23.y);
        out[gidx1] = fmaf(num / den, wo, bo);
    }
}

extern "C" void kernel_launch(void* const* d_in, const int* in_sizes, int n_in,
                              void* d_out, int out_size, void* d_ws, size_t ws_size,
                              hipStream_t stream) {
    const float* q   = (const float*)d_in[0];
    const float* k   = (const float*)d_in[1];
    const float* v   = (const float*)d_in[2];
    const float* ipw = (const float*)d_in[3];
    const float* ipb = (const float*)d_in[4];
    const float* opw = (const float*)d_in[5];
    const float* opb = (const float*)d_in[6];
    float* out = (float*)d_out;

    dim3 grid(NBLK * NN / 2);   // 2048 WGs: two problems each (g, g+2048)
    dim3 block(BSZ);
    BlockCrossAttn_kernel<<<grid, block, 0, stream>>>(q, k, v, ipw, ipb, opw, opb, out);
}